// Round 1
// baseline (1951.944 us; speedup 1.0000x reference)
//
#include <hip/hip_runtime.h>

// Shapes (fixed by the problem)
#define Bx 16
#define Cx 256
#define Dx 32
#define Nx 2304   // 48*48

// ---------------------------------------------------------------------------
// Kernel A: q/k projections.  q[b][d][n] = bq[d] + sum_c Wq[d][c] x[b][c][n]
// grid: 2(q/k) * B * 4(d-chunks of 8) * 9(n-tiles of 256), 256 threads
// ---------------------------------------------------------------------------
__global__ __launch_bounds__(256) void qk_proj(
    const float* __restrict__ x,
    const float* __restrict__ Wq, const float* __restrict__ bq,
    const float* __restrict__ Wk, const float* __restrict__ bk,
    float* __restrict__ qout, float* __restrict__ kout) {
    int bid = blockIdx.x;
    int nt = bid % 9;  bid /= 9;
    int dc = bid % 4;  bid /= 4;
    int b  = bid % Bx; bid /= Bx;
    int qk = bid;  // 0 -> q, 1 -> k
    const float* Wm   = qk ? Wk : Wq;
    const float* bias = qk ? bk : bq;
    float* dst        = qk ? kout : qout;

    int n  = nt * 256 + threadIdx.x;
    int d0 = dc * 8;
    float acc[8];
#pragma unroll
    for (int dd = 0; dd < 8; ++dd) acc[dd] = bias[d0 + dd];

    const float* xcol = x + (size_t)b * Cx * Nx + n;
    for (int c = 0; c < Cx; ++c) {
        float xv = xcol[(size_t)c * Nx];   // coalesced across threads
#pragma unroll
        for (int dd = 0; dd < 8; ++dd)
            acc[dd] += Wm[(d0 + dd) * Cx + c] * xv;  // thread-uniform -> s_load
    }
#pragma unroll
    for (int dd = 0; dd < 8; ++dd)
        dst[((size_t)b * Dx + d0 + dd) * Nx + n] = acc[dd];
}

// ---------------------------------------------------------------------------
// Kernel B: v projection, stored TRANSPOSED: vT[b][n][c_out]
// grid: B * (N/16) = 2304 blocks, 256 threads (thread = c_out)
// ---------------------------------------------------------------------------
__global__ __launch_bounds__(256) void v_proj(
    const float* __restrict__ x,
    const float* __restrict__ Wv, const float* __restrict__ bv,
    float* __restrict__ vT) {
    __shared__ float sx[Cx * 16];   // [c][nn], 16 KB
    int bid = blockIdx.x;
    int nt = bid % (Nx / 16);
    int b  = bid / (Nx / 16);
    int n0 = nt * 16;
    int t  = threadIdx.x;

    // stage x[b][:][n0..n0+15]; 16 consecutive threads read 16 consecutive n
    for (int r = 0; r < 16; ++r) {
        int f = r * 256 + t;
        int c = f >> 4, nn = f & 15;
        sx[f] = x[((size_t)b * Cx + c) * Nx + n0 + nn];
    }
    __syncthreads();

    float acc[16];
    float bvv = bv[t];
#pragma unroll
    for (int nn = 0; nn < 16; ++nn) acc[nn] = bvv;

    const float* wrow = Wv + (size_t)t * Cx;   // Wv[c_out][c]
    for (int c = 0; c < Cx; ++c) {
        float wv = wrow[c];
        const float4* sxr = (const float4*)&sx[c * 16];  // uniform addr -> broadcast
#pragma unroll
        for (int g = 0; g < 4; ++g) {
            float4 xv = sxr[g];
            acc[g * 4 + 0] += wv * xv.x;
            acc[g * 4 + 1] += wv * xv.y;
            acc[g * 4 + 2] += wv * xv.z;
            acc[g * 4 + 3] += wv * xv.w;
        }
    }
    for (int nn = 0; nn < 16; ++nn)
        vT[((size_t)b * Nx + n0 + nn) * Cx + t] = acc[nn];  // coalesced
}

// ---------------------------------------------------------------------------
// Kernel C: softmax column sums.  s[b][j] = sum_i exp(q[:,i] . k[:,j])
// (softmax is over the QUERY axis i -> per-column normalization; |E|<~25 so
//  no max-subtraction needed in fp32)
// grid: B * 9(j-tiles of 256) * 4(i-splits) = 576 blocks, 256 threads
// s must be zeroed before launch; partials combined with atomicAdd.
// ---------------------------------------------------------------------------
__global__ __launch_bounds__(256) void col_stats(
    const float* __restrict__ q, const float* __restrict__ k,
    float* __restrict__ s) {
    __shared__ float sq[64 * 32];  // [il][d], 8 KB
    int bid = blockIdx.x;
    int sp = bid % 4; bid /= 4;
    int jt = bid % 9; bid /= 9;
    int b  = bid;
    int t  = threadIdx.x;
    int j  = jt * 256 + t;

    float kreg[32];
#pragma unroll
    for (int d = 0; d < 32; ++d)
        kreg[d] = k[((size_t)b * Dx + d) * Nx + j];  // coalesced

    float acc = 0.f;
    for (int itile = 0; itile < 9; ++itile) {
        int i0 = sp * 576 + itile * 64;
        __syncthreads();
        for (int r = 0; r < 8; ++r) {          // stage q tile transposed
            int f = r * 256 + t;               // f = d*64 + il
            int d = f >> 6, il = f & 63;
            sq[il * 32 + d] = q[((size_t)b * Dx + d) * Nx + i0 + il];
        }
        __syncthreads();
        for (int il = 0; il < 64; ++il) {
            const float4* qr = (const float4*)&sq[il * 32];  // broadcast reads
            float e = 0.f;
#pragma unroll
            for (int g = 0; g < 8; ++g) {
                float4 qv = qr[g];
                e += qv.x * kreg[g * 4 + 0] + qv.y * kreg[g * 4 + 1]
                   + qv.z * kreg[g * 4 + 2] + qv.w * kreg[g * 4 + 3];
            }
            acc += __expf(e);
        }
    }
    atomicAdd(&s[(size_t)b * Nx + j], acc);
}

// ---------------------------------------------------------------------------
// Kernel D: main.  out[b][c][i] = x + gamma * sum_j exp(E[i,j])/s_j * v[c][j]
// grid: B * 36(i-tiles of 64) = 576 blocks, 256 threads (thread = channel c)
// ---------------------------------------------------------------------------
__global__ __launch_bounds__(256) void attn_out(
    const float* __restrict__ q, const float* __restrict__ k,
    const float* __restrict__ vT, const float* __restrict__ s,
    const float* __restrict__ x, const float* __restrict__ gamma,
    float* __restrict__ out) {
    __shared__ float sq[64 * 32];    // [il][d]   8 KB, staged once
    __shared__ float p [64 * 64];    // [il][j]  16 KB, per j-tile
    __shared__ float ep[256 * 17];   // epilogue transpose, ~17 KB
    int bid = blockIdx.x;
    int it = bid % 36;
    int b  = bid / 36;
    int i0 = it * 64;
    int t  = threadIdx.x;

    for (int r = 0; r < 8; ++r) {      // stage q tile (once per block)
        int f = r * 256 + t;
        int d = f >> 6, il = f & 63;
        sq[il * 32 + d] = q[((size_t)b * Dx + d) * Nx + i0 + il];
    }
    float acc[64];
#pragma unroll
    for (int il = 0; il < 64; ++il) acc[il] = 0.f;

    int jl  = t & 63;    // column within j-tile
    int seg = t >> 6;    // 4 segments each cover 16 query rows
    __syncthreads();

    for (int jt2 = 0; jt2 < 36; ++jt2) {
        // ---- phase 1: P[il][jl] = exp(E)/s_j for this 64x64 tile ----
        int j = jt2 * 64 + jl;
        float kreg[32];
#pragma unroll
        for (int d = 0; d < 32; ++d)
            kreg[d] = k[((size_t)b * Dx + d) * Nx + j];  // 64-lane coalesced
        float rs = 1.0f / s[(size_t)b * Nx + j];
#pragma unroll
        for (int u = 0; u < 16; ++u) {
            int il = seg * 16 + u;
            const float4* qr = (const float4*)&sq[il * 32];
            float e = 0.f;
#pragma unroll
            for (int g = 0; g < 8; ++g) {
                float4 qv = qr[g];
                e += qv.x * kreg[g * 4 + 0] + qv.y * kreg[g * 4 + 1]
                   + qv.z * kreg[g * 4 + 2] + qv.w * kreg[g * 4 + 3];
            }
            p[il * 64 + jl] = __expf(e) * rs;  // conflict-free (jl contiguous)
        }
        __syncthreads();
        // ---- phase 2: acc[il] += P[il][j] * v[c=t][j] ----
        const float* vb = vT + ((size_t)b * Nx + jt2 * 64) * Cx + t;
        for (int jj = 0; jj < 16; ++jj) {
            float v0 = vb[(jj * 4 + 0) * Cx];   // coalesced across threads
            float v1 = vb[(jj * 4 + 1) * Cx];
            float v2 = vb[(jj * 4 + 2) * Cx];
            float v3 = vb[(jj * 4 + 3) * Cx];
#pragma unroll
            for (int il = 0; il < 64; ++il) {
                float4 pv = ((const float4*)&p[il * 64])[jj];  // broadcast b128
                acc[il] += pv.x * v0 + pv.y * v1 + pv.z * v2 + pv.w * v3;
            }
        }
        __syncthreads();
    }

    // ---- epilogue: transpose through LDS so global stores are contiguous ----
    float g = gamma[0];
    for (int chunk = 0; chunk < 4; ++chunk) {
        __syncthreads();
#pragma unroll
        for (int u = 0; u < 16; ++u)
            ep[t * 17 + u] = acc[chunk * 16 + u];  // stride 17: conflict-free
        __syncthreads();
        int r = t & 15, uu = t >> 4;
        int i = i0 + chunk * 16 + r;
        for (int cc = 0; cc < 16; ++cc) {
            int c = cc * 16 + uu;
            float val = ep[c * 17 + r];
            size_t idx = ((size_t)b * Cx + c) * Nx + i;
            out[idx] = x[idx] + g * val;   // 64B-contiguous per 16 lanes
        }
    }
}

// ---------------------------------------------------------------------------
extern "C" void kernel_launch(void* const* d_in, const int* in_sizes, int n_in,
                              void* d_out, int out_size, void* d_ws, size_t ws_size,
                              hipStream_t stream) {
    const float* x     = (const float*)d_in[0];
    const float* Wq    = (const float*)d_in[1];
    const float* bq    = (const float*)d_in[2];
    const float* Wk    = (const float*)d_in[3];
    const float* bk    = (const float*)d_in[4];
    const float* Wv    = (const float*)d_in[5];
    const float* bv    = (const float*)d_in[6];
    const float* gamma = (const float*)d_in[7];
    float* out = (float*)d_out;

    // workspace layout (floats): q | k | vT | s   (~45.1 MB total)
    float* q  = (float*)d_ws;
    float* k  = q  + (size_t)Bx * Dx * Nx;
    float* vT = k  + (size_t)Bx * Dx * Nx;
    float* s  = vT + (size_t)Bx * Nx * Cx;

    hipMemsetAsync(s, 0, (size_t)Bx * Nx * sizeof(float), stream);
    qk_proj  <<<2 * Bx * 4 * 9, 256, 0, stream>>>(x, Wq, bq, Wk, bk, q, k);
    v_proj   <<<Bx * (Nx / 16), 256, 0, stream>>>(x, Wv, bv, vT);
    col_stats<<<Bx * 9 * 4,     256, 0, stream>>>(q, k, s);
    attn_out <<<Bx * 36,        256, 0, stream>>>(q, k, vT, s, x, gamma, out);
}

// Round 2
// 681.707 us; speedup vs baseline: 2.8633x; 2.8633x over previous
//
#include <hip/hip_runtime.h>

// Shapes (fixed by the problem)
#define Bx 16
#define Cx 256
#define Dx 32
#define Nx 2304   // 48*48
#define JT 36     // Nx / 64

typedef _Float16 f16;
typedef _Float16 f16x8 __attribute__((ext_vector_type(8)));
typedef float    f32x4 __attribute__((ext_vector_type(4)));

#define MFMA16(a, b, c) __builtin_amdgcn_mfma_f32_16x16x32_f16((a), (b), (c), 0, 0, 0)

// ---------------------------------------------------------------------------
// Kernel A: q/k projections -> f16 hi/lo, layout [b][n][d] (d contiguous).
// q = Wq x + bq computed in fp32, then split: q = hi + lo (each f16).
// grid: 2(q/k) * B * 4(d-chunks of 8) * 9(n-tiles of 256), 256 threads
// ---------------------------------------------------------------------------
__global__ __launch_bounds__(256) void qk_proj(
    const float* __restrict__ x,
    const float* __restrict__ Wq, const float* __restrict__ bq,
    const float* __restrict__ Wk, const float* __restrict__ bk,
    f16* __restrict__ qhi, f16* __restrict__ qlo,
    f16* __restrict__ khi, f16* __restrict__ klo) {
    int bid = blockIdx.x;
    int nt = bid % 9;  bid /= 9;
    int dc = bid % 4;  bid /= 4;
    int b  = bid % Bx; bid /= Bx;
    int qk = bid;  // 0 -> q, 1 -> k
    const float* Wm   = qk ? Wk : Wq;
    const float* bias = qk ? bk : bq;
    f16* dhi          = qk ? khi : qhi;
    f16* dlo          = qk ? klo : qlo;

    int n  = nt * 256 + threadIdx.x;
    int d0 = dc * 8;
    float acc[8];
#pragma unroll
    for (int dd = 0; dd < 8; ++dd) acc[dd] = bias[d0 + dd];

    const float* xcol = x + (size_t)b * Cx * Nx + n;
    for (int c = 0; c < Cx; ++c) {
        float xv = xcol[(size_t)c * Nx];   // coalesced across threads
#pragma unroll
        for (int dd = 0; dd < 8; ++dd)
            acc[dd] += Wm[(d0 + dd) * Cx + c] * xv;  // thread-uniform -> s_load
    }
    f16x8 hi, lo;
#pragma unroll
    for (int dd = 0; dd < 8; ++dd) {
        f16 h = (f16)acc[dd];
        hi[dd] = h;
        lo[dd] = (f16)(acc[dd] - (float)h);
    }
    size_t base = ((size_t)b * Nx + n) * Dx + d0;   // *2B: 16B-aligned
    *(f16x8*)(dhi + base) = hi;
    *(f16x8*)(dlo + base) = lo;
}

// ---------------------------------------------------------------------------
// Kernel B: v projection -> f16 hi/lo, layout [b][c][n] (n contiguous = the
// PV B-operand "[n][k]" layout with n=c rows, k=j columns).
// grid: B * (N/16) = 2304 blocks, 256 threads (thread = c_out)
// ---------------------------------------------------------------------------
__global__ __launch_bounds__(256) void v_proj(
    const float* __restrict__ x,
    const float* __restrict__ Wv, const float* __restrict__ bv,
    f16* __restrict__ vhi, f16* __restrict__ vlo) {
    __shared__ float sx[Cx * 16];   // [c][nn], 16 KB
    int bid = blockIdx.x;
    int nt = bid % (Nx / 16);
    int b  = bid / (Nx / 16);
    int n0 = nt * 16;
    int t  = threadIdx.x;

    for (int r = 0; r < 16; ++r) {
        int f = r * 256 + t;
        int c = f >> 4, nn = f & 15;
        sx[f] = x[((size_t)b * Cx + c) * Nx + n0 + nn];
    }
    __syncthreads();

    float acc[16];
    float bvv = bv[t];
#pragma unroll
    for (int nn = 0; nn < 16; ++nn) acc[nn] = bvv;

    const float* wrow = Wv + (size_t)t * Cx;   // Wv[c_out][c]
    for (int c = 0; c < Cx; ++c) {
        float wv = wrow[c];
        const float4* sxr = (const float4*)&sx[c * 16];  // uniform -> broadcast
#pragma unroll
        for (int g = 0; g < 4; ++g) {
            float4 xv = sxr[g];
            acc[g * 4 + 0] += wv * xv.x;
            acc[g * 4 + 1] += wv * xv.y;
            acc[g * 4 + 2] += wv * xv.z;
            acc[g * 4 + 3] += wv * xv.w;
        }
    }
    f16x8 h0, l0, h1, l1;
#pragma unroll
    for (int nn = 0; nn < 8; ++nn) {
        f16 h = (f16)acc[nn];
        h0[nn] = h; l0[nn] = (f16)(acc[nn] - (float)h);
    }
#pragma unroll
    for (int nn = 0; nn < 8; ++nn) {
        f16 h = (f16)acc[8 + nn];
        h1[nn] = h; l1[nn] = (f16)(acc[8 + nn] - (float)h);
    }
    size_t base = ((size_t)b * Cx + t) * Nx + n0;   // *2B: 32B-aligned
    *(f16x8*)(vhi + base)     = h0;
    *(f16x8*)(vhi + base + 8) = h1;
    *(f16x8*)(vlo + base)     = l0;
    *(f16x8*)(vlo + base + 8) = l1;
}

// ---------------------------------------------------------------------------
// Kernel C: softmax column sums via MFMA.  s[b][j] = sum_i exp(E[i,j]).
// Block: one (b, j-tile of 64); loops all 36 i-tiles. Wave w computes the
// E-tiles with i-rows [i0 + w*16, +16) x all 4 j-subtiles.
// grid: B * 36 = 576 blocks, 256 threads.
// ---------------------------------------------------------------------------
__global__ __launch_bounds__(256) void col_stats(
    const f16* __restrict__ qhi, const f16* __restrict__ qlo,
    const f16* __restrict__ khi, const f16* __restrict__ klo,
    float* __restrict__ s) {
    __shared__ float sw[4][64];
    int jt = blockIdx.x % JT;
    int b  = blockIdx.x / JT;
    int t  = threadIdx.x, w = t >> 6, l = t & 63;
    int m  = l & 15, q4 = l >> 4;

    // B-operand (K): rows j = jt*64 + tn*16 + m, k-offset q4*8  ([n][k] read)
    f16x8 kh[4], kl[4];
#pragma unroll
    for (int tn = 0; tn < 4; ++tn) {
        size_t off = ((size_t)b * Nx + jt * 64 + tn * 16 + m) * Dx + q4 * 8;
        kh[tn] = *(const f16x8*)(khi + off);
        kl[tn] = *(const f16x8*)(klo + off);
    }
    float sacc[4] = {0.f, 0.f, 0.f, 0.f};
    for (int it = 0; it < JT; ++it) {
        size_t qoff = ((size_t)b * Nx + it * 64 + w * 16 + m) * Dx + q4 * 8;
        f16x8 qh = *(const f16x8*)(qhi + qoff);
        f16x8 ql = *(const f16x8*)(qlo + qoff);
#pragma unroll
        for (int tn = 0; tn < 4; ++tn) {
            f32x4 e = {0.f, 0.f, 0.f, 0.f};
            e = MFMA16(qh, kh[tn], e);   // hi*hi
            e = MFMA16(qh, kl[tn], e);   // hi*lo
            e = MFMA16(ql, kh[tn], e);   // lo*hi
            sacc[tn] += __expf(e[0]) + __expf(e[1]) + __expf(e[2]) + __expf(e[3]);
        }
    }
    // sum over quads (rows within tile), then across waves via LDS
#pragma unroll
    for (int tn = 0; tn < 4; ++tn) {
        sacc[tn] += __shfl_xor(sacc[tn], 16);
        sacc[tn] += __shfl_xor(sacc[tn], 32);
    }
    if (q4 == 0)
#pragma unroll
        for (int tn = 0; tn < 4; ++tn) sw[w][tn * 16 + m] = sacc[tn];
    __syncthreads();
    if (t < 64)
        s[(size_t)b * Nx + jt * 64 + t] = sw[0][t] + sw[1][t] + sw[2][t] + sw[3][t];
}

// ---------------------------------------------------------------------------
// Kernel D: main. Per block: (b, i-tile of 64). Loop over 36 j-tiles:
//   E-tile (64x64) via MFMA -> exp * (1/s_j) -> split hi/lo f16 -> LDS in
//   A-fragment order -> PV MFMA into acc (wave w owns c in [w*64, w*64+64)).
// Epilogue: LDS transpose -> out = x + gamma * acc, float4 stores.
// grid: B * 36 = 576 blocks, 256 threads.
// ---------------------------------------------------------------------------
__global__ __launch_bounds__(256) void attn_out(
    const f16* __restrict__ qhi, const f16* __restrict__ qlo,
    const f16* __restrict__ khi, const f16* __restrict__ klo,
    const f16* __restrict__ vhi, const f16* __restrict__ vlo,
    const float* __restrict__ s, const float* __restrict__ x,
    const float* __restrict__ gamma, float* __restrict__ out) {
    // smem: [phi 8KB | plo 8KB] aliased by epilogue ebuf (17408B), + rs (9216B)
    __shared__ __align__(16) char smem[26624];
    f16*   phi    = (f16*)smem;
    f16*   plo    = (f16*)(smem + 8192);
    float* rs_lds = (float*)(smem + 17408);

    int it = blockIdx.x % JT;
    int b  = blockIdx.x / JT;
    int i0 = it * 64;
    int t  = threadIdx.x, w = t >> 6, l = t & 63;
    int m  = l & 15, q4 = l >> 4;

    // reciprocal softmax sums, staged once (protected by first in-loop barrier)
    for (int r = t; r < Nx; r += 256)
        rs_lds[r] = 1.0f / s[(size_t)b * Nx + r];

    // A-operand (Q) for E: rows i = i0 + w*16 + m — loaded once per block
    size_t qoff = ((size_t)b * Nx + i0 + w * 16 + m) * Dx + q4 * 8;
    f16x8 qh = *(const f16x8*)(qhi + qoff);
    f16x8 ql = *(const f16x8*)(qlo + qoff);

    f32x4 acc[4][4];   // [tm][tn]: i-subtile x c-subtile, wave's c0 = w*64
#pragma unroll
    for (int tm = 0; tm < 4; ++tm)
#pragma unroll
        for (int tn = 0; tn < 4; ++tn) acc[tm][tn] = (f32x4){0.f, 0.f, 0.f, 0.f};

    const f16* vbh = vhi + ((size_t)b * Cx + w * 64) * Nx;
    const f16* vbl = vlo + ((size_t)b * Cx + w * 64) * Nx;

    for (int jt = 0; jt < JT; ++jt) {
        int j0 = jt * 64;
        // ---- E phase: wave w computes rows [w*16, w*16+16) x 64 j ----
        f32x4 e[4];
#pragma unroll
        for (int tn = 0; tn < 4; ++tn) {
            size_t koff = ((size_t)b * Nx + j0 + tn * 16 + m) * Dx + q4 * 8;
            f16x8 kh = *(const f16x8*)(khi + koff);
            f16x8 kl = *(const f16x8*)(klo + koff);
            f32x4 ee = {0.f, 0.f, 0.f, 0.f};
            ee = MFMA16(qh, kh, ee);
            ee = MFMA16(qh, kl, ee);
            ee = MFMA16(ql, kh, ee);
            e[tn] = ee;
        }
        __syncthreads();   // previous PV reads of phi/plo are done
        // exp * rs, split, store to LDS in A-fragment order:
        // flat = ((tm*2+ks)*64 + lane)*8 + jj  with tm=w here.
#pragma unroll
        for (int tn = 0; tn < 4; ++tn) {
            float rs = rs_lds[j0 + tn * 16 + m];
            int ks = tn >> 1;
            int qq = ((tn & 1) << 1) | (m >> 3);
            int flatbase = ((w * 2 + ks) * 64 + qq * 16 + q4 * 4) * 8 + (m & 7);
#pragma unroll
            for (int r = 0; r < 4; ++r) {
                float p = __expf(e[tn][r]) * rs;
                f16 h = (f16)p;
                int fl = flatbase + r * 8;
                phi[fl] = h;
                plo[fl] = (f16)(p - (float)h);
            }
        }
        __syncthreads();   // P tile ready
        // ---- PV phase: acc[i, c] += P[i, j-tile] * V[j-tile, c] ----
#pragma unroll
        for (int ks = 0; ks < 2; ++ks) {
            f16x8 pah[4], pal[4];
#pragma unroll
            for (int tm = 0; tm < 4; ++tm) {
                pah[tm] = *(const f16x8*)&phi[((tm * 2 + ks) * 64 + l) * 8];
                pal[tm] = *(const f16x8*)&plo[((tm * 2 + ks) * 64 + l) * 8];
            }
#pragma unroll
            for (int tn = 0; tn < 4; ++tn) {
                size_t voff = (size_t)(tn * 16 + m) * Nx + j0 + ks * 32 + q4 * 8;
                f16x8 vh = *(const f16x8*)(vbh + voff);
                f16x8 vl = *(const f16x8*)(vbl + voff);
#pragma unroll
                for (int tm = 0; tm < 4; ++tm) {
                    acc[tm][tn] = MFMA16(pah[tm], vh, acc[tm][tn]);
                    acc[tm][tn] = MFMA16(pah[tm], vl, acc[tm][tn]);
                    acc[tm][tn] = MFMA16(pal[tm], vh, acc[tm][tn]);
                }
            }
        }
    }

    // ---- epilogue: per-wave transpose through LDS, coalesced float4 I/O ----
    __syncthreads();   // all PV reads done; safe to alias phi/plo as ebuf
    float* ebw = (float*)smem + w * 1088;   // 16 c-rows x 68 (i + pad)
    float g = gamma[0];
    for (int tn = 0; tn < 4; ++tn) {
#pragma unroll
        for (int tm = 0; tm < 4; ++tm)
#pragma unroll
            for (int r = 0; r < 4; ++r)
                ebw[m * 68 + tm * 16 + q4 * 4 + r] = acc[tm][tn][r];
        __syncthreads();
#pragma unroll
        for (int pass = 0; pass < 4; ++pass) {
            int cr = pass * 4 + q4;
            f32x4 vv = *(const f32x4*)&ebw[cr * 68 + m * 4];
            int c = w * 64 + tn * 16 + cr;
            size_t gidx = ((size_t)b * Cx + c) * Nx + i0 + m * 4;
            f32x4 xv = *(const f32x4*)(x + gidx);
            vv = xv + g * vv;
            *(f32x4*)(out + gidx) = vv;
        }
        __syncthreads();
    }
}

// ---------------------------------------------------------------------------
extern "C" void kernel_launch(void* const* d_in, const int* in_sizes, int n_in,
                              void* d_out, int out_size, void* d_ws, size_t ws_size,
                              hipStream_t stream) {
    const float* x     = (const float*)d_in[0];
    const float* Wq    = (const float*)d_in[1];
    const float* bq    = (const float*)d_in[2];
    const float* Wk    = (const float*)d_in[3];
    const float* bk    = (const float*)d_in[4];
    const float* Wv    = (const float*)d_in[5];
    const float* bv    = (const float*)d_in[6];
    const float* gamma = (const float*)d_in[7];
    float* out = (float*)d_out;

    // ws layout (47.33 MB total, same footprint as the passing R1 kernel):
    // qhi|qlo|khi|klo: [B][N][D] f16  (2.36 MB each)
    // vhi|vlo:         [B][C][N] f16  (18.87 MB each)
    // s:               [B][N]   f32   (147 KB)
    const size_t QK = (size_t)Bx * Nx * Dx;
    const size_t VN = (size_t)Bx * Cx * Nx;
    f16* qhi = (f16*)d_ws;
    f16* qlo = qhi + QK;
    f16* khi = qlo + QK;
    f16* klo = khi + QK;
    f16* vhi = klo + QK;
    f16* vlo = vhi + VN;
    float* s = (float*)(vlo + VN);

    qk_proj  <<<2 * Bx * 4 * 9, 256, 0, stream>>>(x, Wq, bq, Wk, bk, qhi, qlo, khi, klo);
    v_proj   <<<Bx * (Nx / 16), 256, 0, stream>>>(x, Wv, bv, vhi, vlo);
    col_stats<<<Bx * JT,        256, 0, stream>>>(qhi, qlo, khi, klo, s);
    attn_out <<<Bx * JT,        256, 0, stream>>>(qhi, qlo, khi, klo, vhi, vlo, s, x, gamma, out);
}

// Round 3
// 678.565 us; speedup vs baseline: 2.8766x; 1.0046x over previous
//
#include <hip/hip_runtime.h>

// Shapes (fixed by the problem)
#define Bx 16
#define Cx 256
#define Dx 32
#define Nx 2304   // 48*48

typedef _Float16 f16;
typedef _Float16 f16x4 __attribute__((ext_vector_type(4)));
typedef _Float16 f16x8 __attribute__((ext_vector_type(8)));
typedef float    f32x4 __attribute__((ext_vector_type(4)));
typedef float    f32x16 __attribute__((ext_vector_type(16)));

// A,B fragment layouts (gfx950):
//  32x32x16_f16: lane holds A[m=lane%32][k=(lane/32)*8 + 0..7]  (f16x8)
//  32x32x8_f16 : lane holds A[m=lane%32][k=(lane/32)*4 + 0..3]  (f16x4)
//  C/D 32x32   : col=lane&31, row=(reg&3)+8*(reg>>2)+4*(lane>>5)  [guide-verified]
#define MFMA_K16(a, b, c) __builtin_amdgcn_mfma_f32_32x32x16_f16((a), (b), (c), 0, 0, 0)
#define MFMA_K8(a, b, c)  __builtin_amdgcn_mfma_f32_32x32x8f16((a), (b), (c), 0, 0, 0)

// ---------------------------------------------------------------------------
// Kernel A: q/k projections -> f16 hi/lo, layout [b][n][d] (d contiguous).
// (unchanged from R2 — passed)
// ---------------------------------------------------------------------------
__global__ __launch_bounds__(256) void qk_proj(
    const float* __restrict__ x,
    const float* __restrict__ Wq, const float* __restrict__ bq,
    const float* __restrict__ Wk, const float* __restrict__ bk,
    f16* __restrict__ qhi, f16* __restrict__ qlo,
    f16* __restrict__ khi, f16* __restrict__ klo) {
    int bid = blockIdx.x;
    int nt = bid % 9;  bid /= 9;
    int dc = bid % 4;  bid /= 4;
    int b  = bid % Bx; bid /= Bx;
    int qk = bid;  // 0 -> q, 1 -> k
    const float* Wm   = qk ? Wk : Wq;
    const float* bias = qk ? bk : bq;
    f16* dhi          = qk ? khi : qhi;
    f16* dlo          = qk ? klo : qlo;

    int n  = nt * 256 + threadIdx.x;
    int d0 = dc * 8;
    float acc[8];
#pragma unroll
    for (int dd = 0; dd < 8; ++dd) acc[dd] = bias[d0 + dd];

    const float* xcol = x + (size_t)b * Cx * Nx + n;
    for (int c = 0; c < Cx; ++c) {
        float xv = xcol[(size_t)c * Nx];
#pragma unroll
        for (int dd = 0; dd < 8; ++dd)
            acc[dd] += Wm[(d0 + dd) * Cx + c] * xv;
    }
    f16x8 hi, lo;
#pragma unroll
    for (int dd = 0; dd < 8; ++dd) {
        f16 h = (f16)acc[dd];
        hi[dd] = h;
        lo[dd] = (f16)(acc[dd] - (float)h);
    }
    size_t base = ((size_t)b * Nx + n) * Dx + d0;
    *(f16x8*)(dhi + base) = hi;
    *(f16x8*)(dlo + base) = lo;
}

// ---------------------------------------------------------------------------
// Kernel B: v projection -> f16 hi/lo, layout [b][c][n] (n contiguous).
// (unchanged from R2 — passed)
// ---------------------------------------------------------------------------
__global__ __launch_bounds__(256) void v_proj(
    const float* __restrict__ x,
    const float* __restrict__ Wv, const float* __restrict__ bv,
    f16* __restrict__ vhi, f16* __restrict__ vlo) {
    __shared__ float sx[Cx * 16];
    int bid = blockIdx.x;
    int nt = bid % (Nx / 16);
    int b  = bid / (Nx / 16);
    int n0 = nt * 16;
    int t  = threadIdx.x;

    for (int r = 0; r < 16; ++r) {
        int f = r * 256 + t;
        int c = f >> 4, nn = f & 15;
        sx[f] = x[((size_t)b * Cx + c) * Nx + n0 + nn];
    }
    __syncthreads();

    float acc[16];
    float bvv = bv[t];
#pragma unroll
    for (int nn = 0; nn < 16; ++nn) acc[nn] = bvv;

    const float* wrow = Wv + (size_t)t * Cx;
    for (int c = 0; c < Cx; ++c) {
        float wv = wrow[c];
        const float4* sxr = (const float4*)&sx[c * 16];
#pragma unroll
        for (int g = 0; g < 4; ++g) {
            float4 xv = sxr[g];
            acc[g * 4 + 0] += wv * xv.x;
            acc[g * 4 + 1] += wv * xv.y;
            acc[g * 4 + 2] += wv * xv.z;
            acc[g * 4 + 3] += wv * xv.w;
        }
    }
    f16x8 h0, l0, h1, l1;
#pragma unroll
    for (int nn = 0; nn < 8; ++nn) {
        f16 h = (f16)acc[nn];
        h0[nn] = h; l0[nn] = (f16)(acc[nn] - (float)h);
    }
#pragma unroll
    for (int nn = 0; nn < 8; ++nn) {
        f16 h = (f16)acc[8 + nn];
        h1[nn] = h; l1[nn] = (f16)(acc[8 + nn] - (float)h);
    }
    size_t base = ((size_t)b * Cx + t) * Nx + n0;
    *(f16x8*)(vhi + base)     = h0;
    *(f16x8*)(vhi + base + 8) = h1;
    *(f16x8*)(vlo + base)     = l0;
    *(f16x8*)(vlo + base + 8) = l1;
}

// ---------------------------------------------------------------------------
// Kernel C: softmax column sums via E^T MFMA.  s[b][j] = sum_i exp(E[i,j]).
// One wave per (b, j-32 tile); E^T rows = j align with per-reg accumulators.
// grid: Bx * 72 = 1152 blocks, 64 threads.
// ---------------------------------------------------------------------------
__global__ __launch_bounds__(64, 4) void col_stats(
    const f16* __restrict__ qhi, const f16* __restrict__ qlo,
    const f16* __restrict__ khi, const f16* __restrict__ klo,
    float* __restrict__ s) {
    int jt = blockIdx.x % 72;
    int b  = blockIdx.x / 72;
    int j0 = jt * 32;
    int t  = threadIdx.x, il = t & 31, h = t >> 5;

    // K as A-operand: lane holds K[j0+il][d = h*8 + ks*16 + 0..7]
    f16x8 kh[2], kl[2];
#pragma unroll
    for (int ks = 0; ks < 2; ++ks) {
        size_t off = ((size_t)b * Nx + j0 + il) * Dx + h * 8 + ks * 16;
        kh[ks] = *(const f16x8*)(khi + off);
        kl[ks] = *(const f16x8*)(klo + off);
    }
    f32x16 sacc = {};
    for (int it = 0; it < 72; ++it) {
        // Q as B-operand: lane holds Q[i0+il][d = h*8 + ks*16 + 0..7]
        f16x8 qh[2], ql[2];
#pragma unroll
        for (int ks = 0; ks < 2; ++ks) {
            size_t off = ((size_t)b * Nx + it * 32 + il) * Dx + h * 8 + ks * 16;
            qh[ks] = *(const f16x8*)(qhi + off);
            ql[ks] = *(const f16x8*)(qlo + off);
        }
        f32x16 e = {};
        e = MFMA_K16(kh[0], qh[0], e);
        e = MFMA_K16(kh[0], ql[0], e);
        e = MFMA_K16(kl[0], qh[0], e);
        e = MFMA_K16(kh[1], qh[1], e);
        e = MFMA_K16(kh[1], ql[1], e);
        e = MFMA_K16(kl[1], qh[1], e);
#pragma unroll
        for (int r = 0; r < 16; ++r) sacc[r] += __expf(e[r]);
    }
    // reduce across the 32 i-columns (lanes il within each half; xor<=16 stays in half)
#pragma unroll
    for (int r = 0; r < 16; ++r) {
        float v = sacc[r];
        for (int msk = 1; msk <= 16; msk <<= 1) v += __shfl_xor(v, msk);
        if (il == 0)
            s[(size_t)b * Nx + j0 + (r & 3) + 8 * (r >> 2) + 4 * h] = v;
    }
}

// ---------------------------------------------------------------------------
// Kernel D: main.  One wave per (b, i-64 tile, c-64 quarter). No barriers in
// the j-loop: E^T (32x32x16) C-regs feed the PV (32x32x8) B-operand directly
// after exp/scale/f16-split. D = V·P^T = out^T[c][i] -> coalesced stores.
// grid: Bx * 36 * 4 = 2304 blocks, 64 threads.
// ---------------------------------------------------------------------------
__global__ __launch_bounds__(64, 2) void attn_out(
    const f16* __restrict__ qhi, const f16* __restrict__ qlo,
    const f16* __restrict__ khi, const f16* __restrict__ klo,
    const f16* __restrict__ vhi, const f16* __restrict__ vlo,
    const float* __restrict__ s, const float* __restrict__ x,
    const float* __restrict__ gamma, float* __restrict__ out) {
    __shared__ float rs[Nx];   // 9216 B: 1/s for this batch
    int blk = blockIdx.x;
    int w    = blk & 3;  blk >>= 2;     // c-quarter
    int it64 = blk % 36;
    int b    = blk / 36;
    int i0   = it64 * 64;
    int c0   = w * 64;
    int t = threadIdx.x, il = t & 31, h = t >> 5;

    {   // stage reciprocal sums (single wave: barrier is just a waitcnt)
        const f32x4* s4 = (const f32x4*)(s + (size_t)b * Nx);
        f32x4* rs4 = (f32x4*)rs;
        for (int r = t; r < Nx / 4; r += 64) {
            f32x4 v = s4[r];
            rs4[r] = (f32x4){1.0f / v[0], 1.0f / v[1], 1.0f / v[2], 1.0f / v[3]};
        }
    }
    __syncthreads();

    // Q as B-operand for E^T, both i-subtiles, hoisted out of the j-loop
    f16x8 qh[2][2], ql[2][2];   // [itile][ks]
#pragma unroll
    for (int itile = 0; itile < 2; ++itile)
#pragma unroll
        for (int ks = 0; ks < 2; ++ks) {
            size_t off = ((size_t)b * Nx + i0 + itile * 32 + il) * Dx + h * 8 + ks * 16;
            qh[itile][ks] = *(const f16x8*)(qhi + off);
            ql[itile][ks] = *(const f16x8*)(qlo + off);
        }

    f32x16 acc[2][2];  // [itile][cg] : out^T tile [c 32][i 32]
#pragma unroll
    for (int a = 0; a < 2; ++a)
#pragma unroll
        for (int cgi = 0; cgi < 2; ++cgi) acc[a][cgi] = (f32x16){};

    const f16* vbh = vhi + ((size_t)b * Cx + c0) * Nx;
    const f16* vbl = vlo + ((size_t)b * Cx + c0) * Nx;

    for (int jt = 0; jt < 72; ++jt) {
        int j0 = jt * 32;
        // K as A-operand for E^T
        f16x8 kh[2], kl[2];
#pragma unroll
        for (int ks = 0; ks < 2; ++ks) {
            size_t off = ((size_t)b * Nx + j0 + il) * Dx + h * 8 + ks * 16;
            kh[ks] = *(const f16x8*)(khi + off);
            kl[ks] = *(const f16x8*)(klo + off);
        }
        // V as A-operand for PV: lane holds V[c0+cg*32+il][j0 + g*8 + h*4 + 0..3]
        f16x4 vh[2][4], vl[2][4];
#pragma unroll
        for (int cg = 0; cg < 2; ++cg)
#pragma unroll
            for (int g = 0; g < 4; ++g) {
                size_t voff = (size_t)(cg * 32 + il) * Nx + j0 + g * 8 + h * 4;
                vh[cg][g] = *(const f16x4*)(vbh + voff);
                vl[cg][g] = *(const f16x4*)(vbl + voff);
            }
#pragma unroll
        for (int itile = 0; itile < 2; ++itile) {
            // ---- E^T tile: rows j, cols i ----
            f32x16 e = {};
            e = MFMA_K16(kh[0], qh[itile][0], e);
            e = MFMA_K16(kh[0], ql[itile][0], e);
            e = MFMA_K16(kl[0], qh[itile][0], e);
            e = MFMA_K16(kh[1], qh[itile][1], e);
            e = MFMA_K16(kh[1], ql[itile][1], e);
            e = MFMA_K16(kl[1], qh[itile][1], e);
            // ---- P^T = exp(E^T) * rs[j]; C-regs 4g..4g+3 == B-frag of k-block g ----
            f16x4 ph[4], pl[4];
#pragma unroll
            for (int g = 0; g < 4; ++g)
#pragma unroll
                for (int jj = 0; jj < 4; ++jj) {
                    float p = __expf(e[4 * g + jj]) * rs[j0 + jj + 8 * g + 4 * h];
                    f16 hh = (f16)p;
                    ph[g][jj] = hh;
                    pl[g][jj] = (f16)(p - (float)hh);
                }
            // ---- PV: acc[c][i] += V[c][j-block g] * P^T[j-block g][i] ----
#pragma unroll
            for (int cg = 0; cg < 2; ++cg)
#pragma unroll
                for (int g = 0; g < 4; ++g) {
                    acc[itile][cg] = MFMA_K8(vh[cg][g], ph[g], acc[itile][cg]);
                    acc[itile][cg] = MFMA_K8(vh[cg][g], pl[g], acc[itile][cg]);
                    acc[itile][cg] = MFMA_K8(vl[cg][g], ph[g], acc[itile][cg]);
                }
        }
    }

    // ---- epilogue: D rows are c, cols are i -> stores already coalesced ----
    float gm = gamma[0];
#pragma unroll
    for (int itile = 0; itile < 2; ++itile)
#pragma unroll
        for (int cg = 0; cg < 2; ++cg)
#pragma unroll
            for (int r = 0; r < 16; ++r) {
                int c = c0 + cg * 32 + (r & 3) + 8 * (r >> 2) + 4 * h;
                int i = i0 + itile * 32 + il;
                size_t idx = ((size_t)b * Cx + c) * Nx + i;
                out[idx] = x[idx] + gm * acc[itile][cg][r];
            }
}

// ---------------------------------------------------------------------------
extern "C" void kernel_launch(void* const* d_in, const int* in_sizes, int n_in,
                              void* d_out, int out_size, void* d_ws, size_t ws_size,
                              hipStream_t stream) {
    const float* x     = (const float*)d_in[0];
    const float* Wq    = (const float*)d_in[1];
    const float* bq    = (const float*)d_in[2];
    const float* Wk    = (const float*)d_in[3];
    const float* bk    = (const float*)d_in[4];
    const float* Wv    = (const float*)d_in[5];
    const float* bv    = (const float*)d_in[6];
    const float* gamma = (const float*)d_in[7];
    float* out = (float*)d_out;

    // ws layout (47.33 MB, same as R2 which fit):
    const size_t QK = (size_t)Bx * Nx * Dx;
    const size_t VN = (size_t)Bx * Cx * Nx;
    f16* qhi = (f16*)d_ws;
    f16* qlo = qhi + QK;
    f16* khi = qlo + QK;
    f16* klo = khi + QK;
    f16* vhi = klo + QK;
    f16* vlo = vhi + VN;
    float* s = (float*)(vlo + VN);

    qk_proj  <<<2 * Bx * 4 * 9, 256, 0, stream>>>(x, Wq, bq, Wk, bk, qhi, qlo, khi, klo);
    v_proj   <<<Bx * (Nx / 16), 256, 0, stream>>>(x, Wv, bv, vhi, vlo);
    col_stats<<<Bx * 72,        64, 0, stream>>>(qhi, qlo, khi, klo, s);
    attn_out <<<Bx * 36 * 4,    64, 0, stream>>>(qhi, qlo, khi, klo, vhi, vlo, s, x, gamma, out);
}